// Round 15
// baseline (13277.989 us; speedup 1.0000x reference)
//
#include <hip/hip_runtime.h>

namespace {
constexpr int E_ = 512;
constexpr int H_ = 512;
constexpr int O_ = 32;
constexpr int B_ = 64;
constexpr int T_ = 512;
constexpr int RING = 8;
constexpr int FPAD = 16;                               // 64B per flag
constexpr int ESC  = 8;                                // L2-retry tries before LLC escalation
// ws layout (floats)
constexpr size_t H0_OFF   = 0;                         // RING*B*H = 262144
constexpr size_t H1_OFF   = (size_t)RING * B_ * H_;    // 262144
constexpr size_t HF_OFF   = 2 * H1_OFF;                // 524288
constexpr size_t FLAG_OFF = HF_OFF + (size_t)B_ * H_;  // 557056
constexpr size_t FLAG_UINTS = 8u * 32u * FPAD;         // 4096 (L1 consume-flags)
constexpr size_t WS_REQUIRED = (FLAG_OFF + FLAG_UINTS) * 4;
}

typedef float f32x4 __attribute__((ext_vector_type(4)));

// ---- exchange primitives. Producer dual-stores: sc0 (own-XCD L2, fast
// same-XCD visibility) + sc0 sc1 (LLC, cross-XCD fallback). Consumer
// validity-retry loads start at L2 scope (sc0, ~250cyc) and escalate to
// LLC scope (sc0 sc1) after ESC tries -> correct under ANY block->XCD
// mapping; fast when group-per-XCD co-location holds (bid%8 model). ----
__device__ __forceinline__ void l2_ld2k(const float* p, f32x4& a, f32x4& b) {
    asm volatile(
        "global_load_dwordx4 %0, %2, off sc0\n\t"
        "global_load_dwordx4 %1, %2, off offset:1024 sc0\n\t"
        "s_waitcnt vmcnt(0)"
        : "=&v"(a), "=&v"(b) : "v"(p) : "memory");
}
__device__ __forceinline__ void coh_ld2k(const float* p, f32x4& a, f32x4& b) {
    asm volatile(
        "global_load_dwordx4 %0, %2, off sc0 sc1\n\t"
        "global_load_dwordx4 %1, %2, off offset:1024 sc0 sc1\n\t"
        "s_waitcnt vmcnt(0)"
        : "=&v"(a), "=&v"(b) : "v"(p) : "memory");
}
__device__ __forceinline__ void l2_ld4k(const float* p, const float* q,
                                        f32x4& a, f32x4& b, f32x4& c, f32x4& d) {
    asm volatile(
        "global_load_dwordx4 %0, %4, off sc0\n\t"
        "global_load_dwordx4 %1, %4, off offset:1024 sc0\n\t"
        "global_load_dwordx4 %2, %5, off sc0\n\t"
        "global_load_dwordx4 %3, %5, off offset:1024 sc0\n\t"
        "s_waitcnt vmcnt(0)"
        : "=&v"(a), "=&v"(b), "=&v"(c), "=&v"(d) : "v"(p), "v"(q) : "memory");
}
__device__ __forceinline__ void coh_ld4k(const float* p, const float* q,
                                         f32x4& a, f32x4& b, f32x4& c, f32x4& d) {
    asm volatile(
        "global_load_dwordx4 %0, %4, off sc0 sc1\n\t"
        "global_load_dwordx4 %1, %4, off offset:1024 sc0 sc1\n\t"
        "global_load_dwordx4 %2, %5, off sc0 sc1\n\t"
        "global_load_dwordx4 %3, %5, off offset:1024 sc0 sc1\n\t"
        "s_waitcnt vmcnt(0)"
        : "=&v"(a), "=&v"(b), "=&v"(c), "=&v"(d) : "v"(p), "v"(q) : "memory");
}
__device__ __forceinline__ unsigned flag_poll(const unsigned* p) {
    unsigned v;
    asm volatile("global_load_dword %0, %1, off sc0 sc1\n\ts_waitcnt vmcnt(0)"
                 : "=&v"(v) : "v"(p) : "memory");
    return v;
}
__device__ __forceinline__ void dual_store_u(float* p, unsigned v) {
    asm volatile(
        "global_store_dword %0, %1, off sc0\n\t"
        "global_store_dword %0, %1, off sc0 sc1"
        :: "v"(p), "v"(v) : "memory");
}
__device__ __forceinline__ void flag_store(unsigned* p, unsigned v) {
    asm volatile("global_store_dword %0, %1, off sc0 sc1" :: "v"(p), "v"(v) : "memory");
}

__device__ __forceinline__ float fast_tanh(float x) {
    float e = __builtin_amdgcn_exp2f(x * 2.885390081777927f);
    return 1.0f - 2.0f * __builtin_amdgcn_rcpf(e + 1.0f);
}

// pair-combine butterfly: v[4] partials/lane -> full sum of row (lane&3) on every lane
__device__ __forceinline__ float reduce4(const float v[4], int lane) {
    float a[2];
#pragma unroll
    for (int j = 0; j < 2; ++j) {
        const int sel = lane & 1;
        const float mine = sel ? v[2 * j + 1] : v[2 * j];
        const float send = sel ? v[2 * j] : v[2 * j + 1];
        a[j] = mine + __shfl_xor(send, 1, 64);
    }
    const int sel = (lane >> 1) & 1;
    const float mine = sel ? a[1] : a[0];
    const float send = sel ? a[0] : a[1];
    float s = mine + __shfl_xor(send, 2, 64);
    s += __shfl_xor(s, 4, 64);
    s += __shfl_xor(s, 8, 64);
    s += __shfl_xor(s, 16, 64);
    s += __shfl_xor(s, 32, 64);
    return s;
}

// =====================================================================
// r11 structure (validity-epoch handshake, LDS dedup staging, 2 barriers)
// + XCD co-location: bid = n*8 + g puts all 64 blocks of group g on XCD g
// under round-robin dispatch (8 groups x 64 blocks = 8 XCDs x 64 slots).
// Exchange rides the shared per-XCD L2 (sc0), ~4x lower RT than LLC;
// escalation to sc0sc1 preserves correctness if the mapping assumption
// fails. 512 blocks; 8 waves; wave = 4 rows x 4 elems; bounds(512,4).
// =====================================================================
__global__ __launch_bounds__(512, 4) void rnn_pipe14(
    const int* __restrict__ x, const int* __restrict__ seq_lens,
    const float* __restrict__ emb,
    const float* __restrict__ Whx, const float* __restrict__ Whh,
    const float* __restrict__ b_h,
    float* __restrict__ h0_ring, float* __restrict__ h1_ring,
    float* __restrict__ h1_final, unsigned* __restrict__ flags)
{
    const int bid   = blockIdx.x;
    const int g     = bid & 7;           // group -> XCD (bid%8 round-robin model)
    const int rest  = bid >> 3;          // 0..63
    const int layer = rest >> 5;         // 0..1
    const int c     = rest & 31;         // chunk of 16 rows
    const int tid   = threadIdx.x;
    const int wid   = tid >> 6;
    const int lane  = tid & 63;
    const int we    = wid >> 2;          // elem quad (0..1)
    const int wr    = wid & 3;           // row quad (0..3)
    const int rowbase = c * 16 + wr * 4;
    const int eg0   = g * 8 + we * 4;

    // smem: [0..4096) sx buf0 (L0) / sh1 (L1); [4096..8192) sx buf1 (L0);
    //       [8192..12288) sh (both layers)
    __shared__ float smem[12288];
    float* const sxA = smem;
    float* const sxB = smem + 4096;
    float* const sh  = smem + 8192;
    float* const sh1 = smem;

    const float* WxL = Whx + (size_t)layer * H_ * E_;
    const float* WhL = Whh + (size_t)layer * H_ * H_;
    f32x4 wx0[4], wx1[4], wh0[4], wh1[4];
#pragma unroll
    for (int r = 0; r < 4; ++r) {
        const int row = rowbase + r;
        wx0[r] = *(const f32x4*)(WxL + (size_t)row * E_ + (lane << 2));
        wx1[r] = *(const f32x4*)(WxL + (size_t)row * E_ + 256 + (lane << 2));
        wh0[r] = *(const f32x4*)(WhL + (size_t)row * H_ + (lane << 2));
        wh1[r] = *(const f32x4*)(WhL + (size_t)row * H_ + 256 + (lane << 2));
    }
    const float bias = b_h[layer * H_ + rowbase + (lane & 3)];

    int sl4[4];
#pragma unroll
    for (int q = 0; q < 4; ++q) sl4[q] = seq_lens[eg0 + q];
    int Tg = 1;
#pragma unroll
    for (int j = 0; j < 8; ++j) {
        const int s = seq_lens[g * 8 + j];
        Tg = s > Tg ? s : Tg;
    }

    // L1 consume-flags: [8][32] x FPAD
    unsigned* const myflag = flags + ((size_t)(g * 32 + c)) * FPAD;
    const unsigned* const bp = flags + ((size_t)(g * 32 + (lane & 31))) * FPAD;

    const int se  = wid;                 // staging elem = wave id
    const int seg = g * 8 + se;

    long budget = 1l << 22;

    if (layer == 0) {
        // prologue: stage x(0)
        {
            const int tok = x[(size_t)seg * T_];
            *(f32x4*)&sxA[(se << 9) + (lane << 2)] =
                *(const f32x4*)(emb + ((size_t)tok << 9) + (lane << 2));
            *(f32x4*)&sxA[(se << 9) + 256 + (lane << 2)] =
                *(const f32x4*)(emb + ((size_t)tok << 9) + 256 + (lane << 2));
        }
        __syncthreads();

        for (int t = 0; t < Tg; ++t) {
            const int cur = t & 1, slot = t & 7, pslot = (t - 1) & 7;
            float* const sxc = cur ? sxB : sxA;
            float* const sxn = cur ? sxA : sxB;
            const unsigned em_prev = (((t - 1) >> 3) & 1) ? 0xFFFFFFFFu : 0u;
            const unsigned em_cur  = ((t >> 3) & 1) ? 0xFFFFFFFFu : 0u;

            // ---- backpressure (wave0, t>=RING): all L1 chunks consumed t-8 ----
            if (wid == 0 && t >= RING) {
                const int tgt = t - 7;
                for (;;) {
                    const unsigned v = flag_poll(bp);
                    const bool bad = (lane < 32) && ((int)v < tgt);
                    if (!__any(bad)) break;
                    if (--budget < 0) break;
                }
            }

            // ---- stage h0(t-1), validity-retry (L2 first, LLC after ESC) ----
            if (t > 0) {
                const float* src = h0_ring + (((size_t)pslot << 6) + seg) * 512 + (lane << 2);
                f32x4 da, db;
                int tries = 0;
                for (;;) {
                    f32x4 a, b;
                    if (tries < ESC) l2_ld2k(src, a, b); else coh_ld2k(src, a, b);
                    unsigned o = 0;
#pragma unroll
                    for (int m = 0; m < 4; ++m) {
                        unsigned u = __float_as_uint(a[m]) ^ em_prev; o |= u; da[m] = __uint_as_float(u);
                        unsigned w = __float_as_uint(b[m]) ^ em_prev; o |= w; db[m] = __uint_as_float(w);
                    }
                    if (!__any((o >> 30) & 1)) break;
                    ++tries;
                    if (--budget < 0) break;
                }
                *(f32x4*)&sh[(se << 9) + (lane << 2)] = da;
                *(f32x4*)&sh[(se << 9) + 256 + (lane << 2)] = db;
            } else {
                f32x4 z = 0;
                *(f32x4*)&sh[(se << 9) + (lane << 2)] = z;
                *(f32x4*)&sh[(se << 9) + 256 + (lane << 2)] = z;
            }
            // prefetch x(t+1)
            f32x4 px0, px1;
            const bool havepf = (t + 1 < Tg);
            if (havepf) {
                const int tok = x[(size_t)seg * T_ + t + 1];
                px0 = *(const f32x4*)(emb + ((size_t)tok << 9) + (lane << 2));
                px1 = *(const f32x4*)(emb + ((size_t)tok << 9) + 256 + (lane << 2));
            }
            __syncthreads();                       // barrier 1: sh ready

            // ---- compute + encoded dual-store ----
#pragma unroll
            for (int q = 0; q < 4; ++q) {
                unsigned uenc = em_cur;            // encoded 0.0 for finished elems
                if (t < sl4[q]) {
                    const int el = (we << 2) + q;
                    const f32x4 lx0 = *(const f32x4*)&sxc[(el << 9) + (lane << 2)];
                    const f32x4 lx1 = *(const f32x4*)&sxc[(el << 9) + 256 + (lane << 2)];
                    const f32x4 h0a = *(const f32x4*)&sh[(el << 9) + (lane << 2)];
                    const f32x4 h0b = *(const f32x4*)&sh[(el << 9) + 256 + (lane << 2)];
                    float vv[4];
#pragma unroll
                    for (int r = 0; r < 4; ++r) {
                        float s = wx0[r][0] * lx0[0];
                        s = fmaf(wx0[r][1], lx0[1], s);
                        s = fmaf(wx0[r][2], lx0[2], s);
                        s = fmaf(wx0[r][3], lx0[3], s);
                        s = fmaf(wx1[r][0], lx1[0], s);
                        s = fmaf(wx1[r][1], lx1[1], s);
                        s = fmaf(wx1[r][2], lx1[2], s);
                        s = fmaf(wx1[r][3], lx1[3], s);
                        s = fmaf(wh0[r][0], h0a[0], s);
                        s = fmaf(wh0[r][1], h0a[1], s);
                        s = fmaf(wh0[r][2], h0a[2], s);
                        s = fmaf(wh0[r][3], h0a[3], s);
                        s = fmaf(wh1[r][0], h0b[0], s);
                        s = fmaf(wh1[r][1], h0b[1], s);
                        s = fmaf(wh1[r][2], h0b[2], s);
                        s = fmaf(wh1[r][3], h0b[3], s);
                        vv[r] = s;
                    }
                    const float sum = reduce4(vv, lane);
                    const float hv = fast_tanh(sum + bias);
                    uenc = __float_as_uint(hv) ^ em_cur;
                }
                if (lane < 4)
                    dual_store_u(h0_ring + (((size_t)slot << 6) + eg0 + q) * 512 + rowbase + lane, uenc);
            }
            if (havepf) {
                *(f32x4*)&sxn[(se << 9) + (lane << 2)] = px0;
                *(f32x4*)&sxn[(se << 9) + 256 + (lane << 2)] = px1;
            }
            __syncthreads();                       // barrier 2
        }
    } else {
        // ---- layer 1 ----
        for (int t = 0; t < Tg; ++t) {
            const int slot = t & 7, pslot = (t - 1) & 7;
            const unsigned em0 = ((t >> 3) & 1) ? 0xFFFFFFFFu : 0u;          // h0(t)
            const unsigned em1 = (((t - 1) >> 3) & 1) ? 0xFFFFFFFFu : 0u;    // h1(t-1)

            // ---- stage h0(t) -> sh and h1(t-1) -> sh1, validity-retry ----
            const float* p0 = h0_ring + (((size_t)slot << 6) + seg) * 512 + (lane << 2);
            if (t > 0) {
                const float* p1 = h1_ring + (((size_t)pslot << 6) + seg) * 512 + (lane << 2);
                f32x4 d0a, d0b, d1a, d1b;
                int tries = 0;
                for (;;) {
                    f32x4 a, b, c2, d2;
                    if (tries < ESC) l2_ld4k(p0, p1, a, b, c2, d2);
                    else             coh_ld4k(p0, p1, a, b, c2, d2);
                    unsigned o = 0;
#pragma unroll
                    for (int m = 0; m < 4; ++m) {
                        unsigned u0 = __float_as_uint(a[m])  ^ em0; o |= u0; d0a[m] = __uint_as_float(u0);
                        unsigned u1 = __float_as_uint(b[m])  ^ em0; o |= u1; d0b[m] = __uint_as_float(u1);
                        unsigned u2 = __float_as_uint(c2[m]) ^ em1; o |= u2; d1a[m] = __uint_as_float(u2);
                        unsigned u3 = __float_as_uint(d2[m]) ^ em1; o |= u3; d1b[m] = __uint_as_float(u3);
                    }
                    if (!__any((o >> 30) & 1)) break;
                    ++tries;
                    if (--budget < 0) break;
                }
                *(f32x4*)&sh[(se << 9) + (lane << 2)] = d0a;
                *(f32x4*)&sh[(se << 9) + 256 + (lane << 2)] = d0b;
                *(f32x4*)&sh1[(se << 9) + (lane << 2)] = d1a;
                *(f32x4*)&sh1[(se << 9) + 256 + (lane << 2)] = d1b;
            } else {
                f32x4 d0a, d0b;
                int tries = 0;
                for (;;) {
                    f32x4 a, b;
                    if (tries < ESC) l2_ld2k(p0, a, b); else coh_ld2k(p0, a, b);
                    unsigned o = 0;
#pragma unroll
                    for (int m = 0; m < 4; ++m) {
                        unsigned u0 = __float_as_uint(a[m]) ^ em0; o |= u0; d0a[m] = __uint_as_float(u0);
                        unsigned u1 = __float_as_uint(b[m]) ^ em0; o |= u1; d0b[m] = __uint_as_float(u1);
                    }
                    if (!__any((o >> 30) & 1)) break;
                    ++tries;
                    if (--budget < 0) break;
                }
                *(f32x4*)&sh[(se << 9) + (lane << 2)] = d0a;
                *(f32x4*)&sh[(se << 9) + 256 + (lane << 2)] = d0b;
                f32x4 z = 0;
                *(f32x4*)&sh1[(se << 9) + (lane << 2)] = z;
                *(f32x4*)&sh1[(se << 9) + 256 + (lane << 2)] = z;
            }
            __syncthreads();                       // barrier 1: staged
            if (tid == 0) flag_store(myflag, (unsigned)(t + 1));   // consumed t

#pragma unroll
            for (int q = 0; q < 4; ++q) {
                unsigned uenc = em0;
                const bool live = (t < sl4[q]);
                float hv = 0.f;
                if (live) {
                    const int el = (we << 2) + q;
                    const f32x4 xa = *(const f32x4*)&sh[(el << 9) + (lane << 2)];
                    const f32x4 xb = *(const f32x4*)&sh[(el << 9) + 256 + (lane << 2)];
                    const f32x4 ha = *(const f32x4*)&sh1[(el << 9) + (lane << 2)];
                    const f32x4 hb = *(const f32x4*)&sh1[(el << 9) + 256 + (lane << 2)];
                    float vv[4];
#pragma unroll
                    for (int r = 0; r < 4; ++r) {
                        float s = wx0[r][0] * xa[0];
                        s = fmaf(wx0[r][1], xa[1], s);
                        s = fmaf(wx0[r][2], xa[2], s);
                        s = fmaf(wx0[r][3], xa[3], s);
                        s = fmaf(wx1[r][0], xb[0], s);
                        s = fmaf(wx1[r][1], xb[1], s);
                        s = fmaf(wx1[r][2], xb[2], s);
                        s = fmaf(wx1[r][3], xb[3], s);
                        s = fmaf(wh0[r][0], ha[0], s);
                        s = fmaf(wh0[r][1], ha[1], s);
                        s = fmaf(wh0[r][2], ha[2], s);
                        s = fmaf(wh0[r][3], ha[3], s);
                        s = fmaf(wh1[r][0], hb[0], s);
                        s = fmaf(wh1[r][1], hb[1], s);
                        s = fmaf(wh1[r][2], hb[2], s);
                        s = fmaf(wh1[r][3], hb[3], s);
                        vv[r] = s;
                    }
                    const float sum = reduce4(vv, lane);
                    hv = fast_tanh(sum + bias);
                    uenc = __float_as_uint(hv) ^ em0;
                }
                if (lane < 4) {
                    dual_store_u(h1_ring + (((size_t)slot << 6) + eg0 + q) * 512 + rowbase + lane, uenc);
                    if (live && t == sl4[q] - 1)
                        h1_final[((size_t)(eg0 + q) << 9) + rowbase + lane] = hv;
                }
            }
            __syncthreads();                       // barrier 2
        }
    }
}

// ---- final head: y = Wyh[1] @ h1 + b_y[1]; out = Wf @ y + bf ----
__device__ __forceinline__ float dot4(float4 a, float4 b) {
    return fmaf(a.x, b.x, fmaf(a.y, b.y, fmaf(a.z, b.z, a.w * b.w)));
}
__device__ __forceinline__ float wave_reduce(float acc) {
#pragma unroll
    for (int off = 32; off > 0; off >>= 1) acc += __shfl_down(acc, off, 64);
    return acc;
}

__global__ __launch_bounds__(512) void head_kernel(
    const float* __restrict__ h1f, const float* __restrict__ Wyh,
    const float* __restrict__ b_y, const float* __restrict__ Wf,
    const float* __restrict__ bf, float* __restrict__ out)
{
    const int e = blockIdx.x;
    const int tid = threadIdx.x, wid = tid >> 6, lane = tid & 63;
    const int k0 = lane << 3;
    __shared__ float sh[H_];
    __shared__ float sy[H_];
    sh[tid] = h1f[(size_t)e * H_ + tid];
    __syncthreads();
    const float4 hA = *(const float4*)&sh[k0];
    const float4 hB = *(const float4*)&sh[k0 + 4];
    const float* Wy1 = Wyh + H_ * H_;
#pragma unroll 4
    for (int rr = 0; rr < 64; ++rr) {
        const int row = (wid << 6) + rr;
        float acc = wave_reduce(dot4(*(const float4*)&Wy1[(size_t)row * H_ + k0], hA) +
                                dot4(*(const float4*)&Wy1[(size_t)row * H_ + k0 + 4], hB));
        if (lane == 0) sy[row] = acc + b_y[H_ + row];
    }
    __syncthreads();
    const float4 yA = *(const float4*)&sy[k0];
    const float4 yB = *(const float4*)&sy[k0 + 4];
#pragma unroll
    for (int rr = 0; rr < 4; ++rr) {
        const int o = (wid << 2) + rr;
        float acc = wave_reduce(dot4(*(const float4*)&Wf[(size_t)o * H_ + k0], yA) +
                                dot4(*(const float4*)&Wf[(size_t)o * H_ + k0 + 4], yB));
        if (lane == 0) out[(size_t)e * O_ + o] = acc + bf[o];
    }
}

// ---- fallback (round-0, known-passing) ----
__global__ __launch_bounds__(1024, 1) void rnn_fused_fb(
    const int* __restrict__ x, const int* __restrict__ seq_lens,
    const float* __restrict__ emb, const float* __restrict__ Whx,
    const float* __restrict__ Whh, const float* __restrict__ b_h,
    const float* __restrict__ Wyh, const float* __restrict__ b_y,
    const float* __restrict__ Wf, const float* __restrict__ bf,
    float* __restrict__ out)
{
    const int b = blockIdx.x, tid = threadIdx.x;
    const int wave = tid >> 6, lane = tid & 63, k0 = lane << 3;
    __shared__ float s_inp[E_];
    __shared__ float s_h0[2][H_];
    __shared__ float s_h1[2][H_];
    __shared__ float s_y[H_];
    if (tid < H_) { s_h0[0][tid]=0.f; s_h0[1][tid]=0.f; s_h1[0][tid]=0.f; s_h1[1][tid]=0.f; }
    const int Tb = seq_lens[b];
    const float* Whx0 = Whx; const float* Whx1 = Whx + H_*E_;
    const float* Whh0 = Whh; const float* Whh1 = Whh + H_*H_;
    for (int t = 0; t < Tb; ++t) {
        const int cur = t & 1, prv = cur ^ 1;
        if (tid < E_) { const int tok = x[b*T_+t]; s_inp[tid] = emb[(size_t)tok*E_+tid]; }
        __syncthreads();
        const float4 iA = *(const float4*)&s_inp[k0], iB = *(const float4*)&s_inp[k0+4];
        const float4 pA = *(const float4*)&s_h0[prv][k0], pB = *(const float4*)&s_h0[prv][k0+4];
#pragma unroll 4
        for (int r = 0; r < 32; ++r) {
            const int i = (wave<<5)+r;
            float acc = dot4(*(const float4*)&Whx0[i*E_+k0], iA) + dot4(*(const float4*)&Whx0[i*E_+k0+4], iB)
                      + dot4(*(const float4*)&Whh0[i*H_+k0], pA) + dot4(*(const float4*)&Whh0[i*H_+k0+4], pB);
            acc = wave_reduce(acc);
            if (lane == 0) s_h0[cur][i] = tanhf(acc + b_h[i]);
        }
        __syncthreads();
        const float4 cA = *(const float4*)&s_h0[cur][k0], cB = *(const float4*)&s_h0[cur][k0+4];
        const float4 qA = *(const float4*)&s_h1[prv][k0], qB = *(const float4*)&s_h1[prv][k0+4];
#pragma unroll 4
        for (int r = 0; r < 32; ++r) {
            const int i = (wave<<5)+r;
            float acc = dot4(*(const float4*)&Whx1[i*E_+k0], cA) + dot4(*(const float4*)&Whx1[i*E_+k0+4], cB)
                      + dot4(*(const float4*)&Whh1[i*H_+k0], qA) + dot4(*(const float4*)&Whh1[i*H_+k0+4], qB);
            acc = wave_reduce(acc);
            if (lane == 0) s_h1[cur][i] = tanhf(acc + b_h[H_+i]);
        }
        __syncthreads();
    }
    const int lastb = (Tb-1) & 1;
    const float4 hA = *(const float4*)&s_h1[lastb][k0], hB = *(const float4*)&s_h1[lastb][k0+4];
    const float* Wy1 = Wyh + H_*H_;
#pragma unroll 4
    for (int r = 0; r < 32; ++r) {
        const int i = (wave<<5)+r;
        float acc = wave_reduce(dot4(*(const float4*)&Wy1[i*H_+k0], hA) + dot4(*(const float4*)&Wy1[i*H_+k0+4], hB));
        if (lane == 0) s_y[i] = acc + b_y[H_+i];
    }
    __syncthreads();
    const float4 yA = *(const float4*)&s_y[k0], yB = *(const float4*)&s_y[k0+4];
    if (wave < 8) {
#pragma unroll
        for (int r = 0; r < 4; ++r) {
            const int o = (wave<<2)+r;
            float acc = wave_reduce(dot4(*(const float4*)&Wf[o*H_+k0], yA) + dot4(*(const float4*)&Wf[o*H_+k0+4], yB));
            if (lane == 0) out[b*O_+o] = acc + bf[o];
        }
    }
}

extern "C" void kernel_launch(void* const* d_in, const int* in_sizes, int n_in,
                              void* d_out, int out_size, void* d_ws, size_t ws_size,
                              hipStream_t stream) {
    const int*   x    = (const int*)d_in[0];
    const int*   sl   = (const int*)d_in[1];
    const float* emb  = (const float*)d_in[2];
    const float* Whx  = (const float*)d_in[3];
    const float* Whh  = (const float*)d_in[4];
    const float* b_h  = (const float*)d_in[5];
    const float* Wyh  = (const float*)d_in[6];
    const float* b_y  = (const float*)d_in[7];
    const float* Wf   = (const float*)d_in[8];
    const float* bf   = (const float*)d_in[9];
    float* out = (float*)d_out;

    if (ws_size < WS_REQUIRED) {
        rnn_fused_fb<<<B_, 1024, 0, stream>>>(x, sl, emb, Whx, Whh, b_h, Wyh, b_y, Wf, bf, out);
        return;
    }

    float* ws_f = (float*)d_ws;
    float* h0_ring = ws_f + H0_OFF;
    float* h1_ring = ws_f + H1_OFF;
    float* h1f     = ws_f + HF_OFF;
    unsigned* flags = (unsigned*)(ws_f + FLAG_OFF);

    // rings poisoned to 0xFF (exponent 255 -> stale for epoch 0); flags zeroed
    hipMemsetAsync(h0_ring, 0xFF, 2 * H1_OFF * sizeof(float), stream);
    hipMemsetAsync(flags, 0, FLAG_UINTS * sizeof(unsigned), stream);
    rnn_pipe14<<<512, 512, 0, stream>>>(x, sl, emb, Whx, Whh, b_h,
                                        h0_ring, h1_ring, h1f, flags);
    head_kernel<<<B_, 512, 0, stream>>>(h1f, Wyh, b_y, Wf, bf, out);
}

// Round 16
// 1942.846 us; speedup vs baseline: 6.8343x; 6.8343x over previous
//
#include <hip/hip_runtime.h>

namespace {
constexpr int E_ = 512;
constexpr int H_ = 512;
constexpr int O_ = 32;
constexpr int B_ = 64;
constexpr int T_ = 512;
constexpr int RING = 8;
constexpr int FPAD = 16;                               // 64B per flag
// ws layout (floats)
constexpr size_t H0_OFF   = 0;                         // RING*B*H = 262144
constexpr size_t H1_OFF   = (size_t)RING * B_ * H_;    // 262144
constexpr size_t HF_OFF   = 2 * H1_OFF;                // 524288
constexpr size_t FLAG_OFF = HF_OFF + (size_t)B_ * H_;  // 557056
constexpr size_t FLAG_UINTS = 8u * 32u * FPAD;         // 4096 (L1 consume-flags only)
constexpr size_t WS_REQUIRED = (FLAG_OFF + FLAG_UINTS) * 4;
}

typedef float f32x4 __attribute__((ext_vector_type(4)));

// ---- coherent LLC primitives; self-contained (waitcnt inside asm) ----
__device__ __forceinline__ void coh_ld2k(const float* p, f32x4& a, f32x4& b) {
    asm volatile(
        "global_load_dwordx4 %0, %2, off sc0 sc1\n\t"
        "global_load_dwordx4 %1, %2, off offset:1024 sc0 sc1\n\t"
        "s_waitcnt vmcnt(0)"
        : "=&v"(a), "=&v"(b) : "v"(p) : "memory");
}
__device__ __forceinline__ void coh_ld4k(const float* p, const float* q,
                                         f32x4& a, f32x4& b, f32x4& c, f32x4& d) {
    asm volatile(
        "global_load_dwordx4 %0, %4, off sc0 sc1\n\t"
        "global_load_dwordx4 %1, %4, off offset:1024 sc0 sc1\n\t"
        "global_load_dwordx4 %2, %5, off sc0 sc1\n\t"
        "global_load_dwordx4 %3, %5, off offset:1024 sc0 sc1\n\t"
        "s_waitcnt vmcnt(0)"
        : "=&v"(a), "=&v"(b), "=&v"(c), "=&v"(d) : "v"(p), "v"(q) : "memory");
}
__device__ __forceinline__ unsigned flag_poll(const unsigned* p) {
    unsigned v;
    asm volatile("global_load_dword %0, %1, off sc0 sc1\n\ts_waitcnt vmcnt(0)"
                 : "=&v"(v) : "v"(p) : "memory");
    return v;
}
__device__ __forceinline__ void coh_store_u(float* p, unsigned v) {
    asm volatile("global_store_dword %0, %1, off sc0 sc1" :: "v"(p), "v"(v) : "memory");
}
__device__ __forceinline__ void flag_store(unsigned* p, unsigned v) {
    asm volatile("global_store_dword %0, %1, off sc0 sc1" :: "v"(p), "v"(v) : "memory");
}

__device__ __forceinline__ float fast_tanh(float x) {
    float e = __builtin_amdgcn_exp2f(x * 2.885390081777927f);
    return 1.0f - 2.0f * __builtin_amdgcn_rcpf(e + 1.0f);
}

// pair-combine butterfly: v[4] partials/lane -> full sum of row (lane&3) on every lane
__device__ __forceinline__ float reduce4(const float v[4], int lane) {
    float a[2];
#pragma unroll
    for (int j = 0; j < 2; ++j) {
        const int sel = lane & 1;
        const float mine = sel ? v[2 * j + 1] : v[2 * j];
        const float send = sel ? v[2 * j] : v[2 * j + 1];
        a[j] = mine + __shfl_xor(send, 1, 64);
    }
    const int sel = (lane >> 1) & 1;
    const float mine = sel ? a[1] : a[0];
    const float send = sel ? a[0] : a[1];
    float s = mine + __shfl_xor(send, 2, 64);
    s += __shfl_xor(s, 4, 64);
    s += __shfl_xor(s, 8, 64);
    s += __shfl_xor(s, 16, 64);
    s += __shfl_xor(s, 32, 64);
    return s;
}

// =====================================================================
// Best-known configuration (round 11, 1938 us): 512 blocks = 2 layers x
// 8 groups(8 elems) x 32 chunks(16 rows); 8 waves; wave = 4 rows x 4 elems;
// bounds(512,4) -> 2 blocks/CU; LDS dedup staging (per-wave reg loads =
// 128x redundancy = 19GB HBM, r10); DATA-VALIDITY handshake: h stored as
// bits(h) XOR epoch-mask (epoch=(t>>3)&1; |tanh|<=1 -> bit30 encodes the
// epoch). Stage-load XOR-decode doubles as the freshness check -> poll and
// stage merged into ONE LLC round trip; no vm_drain or L0 flag stores on
// the critical path. L1 posts consume-flags only (ring backpressure, 8-step
// slack). Exchange scope MUST be LLC (sc0 sc1): consumer-side L2 serves
// stale lines forever under remote stores (r14, 6.8x regression).
// =====================================================================
__global__ __launch_bounds__(512, 4) void rnn_pipe11(
    const int* __restrict__ x, const int* __restrict__ seq_lens,
    const float* __restrict__ emb,
    const float* __restrict__ Whx, const float* __restrict__ Whh,
    const float* __restrict__ b_h,
    float* __restrict__ h0_ring, float* __restrict__ h1_ring,
    float* __restrict__ h1_final, unsigned* __restrict__ flags)
{
    const int bid   = blockIdx.x;
    const int layer = bid >> 8;          // 0..1
    const int g     = (bid >> 5) & 7;    // group of 8 elems
    const int c     = bid & 31;          // chunk of 16 rows
    const int tid   = threadIdx.x;
    const int wid   = tid >> 6;
    const int lane  = tid & 63;
    const int we    = wid >> 2;          // elem quad (0..1)
    const int wr    = wid & 3;           // row quad (0..3)
    const int rowbase = c * 16 + wr * 4;
    const int eg0   = g * 8 + we * 4;

    // smem: [0..4096) sx buf0 (L0) / sh1 (L1); [4096..8192) sx buf1 (L0);
    //       [8192..12288) sh (both layers)
    __shared__ float smem[12288];
    float* const sxA = smem;
    float* const sxB = smem + 4096;
    float* const sh  = smem + 8192;
    float* const sh1 = smem;

    const float* WxL = Whx + (size_t)layer * H_ * E_;
    const float* WhL = Whh + (size_t)layer * H_ * H_;
    f32x4 wx0[4], wx1[4], wh0[4], wh1[4];
#pragma unroll
    for (int r = 0; r < 4; ++r) {
        const int row = rowbase + r;
        wx0[r] = *(const f32x4*)(WxL + (size_t)row * E_ + (lane << 2));
        wx1[r] = *(const f32x4*)(WxL + (size_t)row * E_ + 256 + (lane << 2));
        wh0[r] = *(const f32x4*)(WhL + (size_t)row * H_ + (lane << 2));
        wh1[r] = *(const f32x4*)(WhL + (size_t)row * H_ + 256 + (lane << 2));
    }
    const float bias = b_h[layer * H_ + rowbase + (lane & 3)];

    int sl4[4];
#pragma unroll
    for (int q = 0; q < 4; ++q) sl4[q] = seq_lens[eg0 + q];
    int Tg = 1;
#pragma unroll
    for (int j = 0; j < 8; ++j) {
        const int s = seq_lens[g * 8 + j];
        Tg = s > Tg ? s : Tg;
    }

    // L1 consume-flags: [8][32] x FPAD
    unsigned* const myflag = flags + ((size_t)(g * 32 + c)) * FPAD;
    const unsigned* const bp = flags + ((size_t)(g * 32 + (lane & 31))) * FPAD;

    const int se  = wid;                 // staging elem = wave id
    const int seg = g * 8 + se;

    long budget = 1l << 22;

    if (layer == 0) {
        // prologue: stage x(0)
        {
            const int tok = x[(size_t)seg * T_];
            *(f32x4*)&sxA[(se << 9) + (lane << 2)] =
                *(const f32x4*)(emb + ((size_t)tok << 9) + (lane << 2));
            *(f32x4*)&sxA[(se << 9) + 256 + (lane << 2)] =
                *(const f32x4*)(emb + ((size_t)tok << 9) + 256 + (lane << 2));
        }
        __syncthreads();

        for (int t = 0; t < Tg; ++t) {
            const int cur = t & 1, slot = t & 7, pslot = (t - 1) & 7;
            float* const sxc = cur ? sxB : sxA;
            float* const sxn = cur ? sxA : sxB;
            const unsigned em_prev = (((t - 1) >> 3) & 1) ? 0xFFFFFFFFu : 0u;
            const unsigned em_cur  = ((t >> 3) & 1) ? 0xFFFFFFFFu : 0u;

            // ---- backpressure (wave0, t>=RING): all L1 chunks consumed t-8 ----
            if (wid == 0 && t >= RING) {
                const int tgt = t - 7;
                for (;;) {
                    const unsigned v = flag_poll(bp);
                    const bool bad = (lane < 32) && ((int)v < tgt);
                    if (!__any(bad)) break;
                    if (--budget < 0) break;
                }
            }

            // ---- stage h0(t-1) with validity-retry; decode doubles as check ----
            if (t > 0) {
                const float* src = h0_ring + (((size_t)pslot << 6) + seg) * 512 + (lane << 2);
                f32x4 da, db;
                for (;;) {
                    f32x4 a, b;
                    coh_ld2k(src, a, b);
                    unsigned o = 0;
#pragma unroll
                    for (int m = 0; m < 4; ++m) {
                        unsigned u = __float_as_uint(a[m]) ^ em_prev; o |= u; da[m] = __uint_as_float(u);
                        unsigned w = __float_as_uint(b[m]) ^ em_prev; o |= w; db[m] = __uint_as_float(w);
                    }
                    if (!__any((o >> 30) & 1)) break;
                    if (--budget < 0) break;
                }
                *(f32x4*)&sh[(se << 9) + (lane << 2)] = da;
                *(f32x4*)&sh[(se << 9) + 256 + (lane << 2)] = db;
            } else {
                f32x4 z = 0;
                *(f32x4*)&sh[(se << 9) + (lane << 2)] = z;
                *(f32x4*)&sh[(se << 9) + 256 + (lane << 2)] = z;
            }
            // prefetch x(t+1)
            f32x4 px0, px1;
            const bool havepf = (t + 1 < Tg);
            if (havepf) {
                const int tok = x[(size_t)seg * T_ + t + 1];
                px0 = *(const f32x4*)(emb + ((size_t)tok << 9) + (lane << 2));
                px1 = *(const f32x4*)(emb + ((size_t)tok << 9) + 256 + (lane << 2));
            }
            __syncthreads();                       // barrier 1: sh ready

            // ---- compute + encoded store (always store: validity must progress) ----
#pragma unroll
            for (int q = 0; q < 4; ++q) {
                unsigned uenc = em_cur;            // encoded 0.0 for finished elems
                if (t < sl4[q]) {
                    const int el = (we << 2) + q;
                    const f32x4 lx0 = *(const f32x4*)&sxc[(el << 9) + (lane << 2)];
                    const f32x4 lx1 = *(const f32x4*)&sxc[(el << 9) + 256 + (lane << 2)];
                    const f32x4 h0a = *(const f32x4*)&sh[(el << 9) + (lane << 2)];
                    const f32x4 h0b = *(const f32x4*)&sh[(el << 9) + 256 + (lane << 2)];
                    float vv[4];
#pragma unroll
                    for (int r = 0; r < 4; ++r) {
                        float s = wx0[r][0] * lx0[0];
                        s = fmaf(wx0[r][1], lx0[1], s);
                        s = fmaf(wx0[r][2], lx0[2], s);
                        s = fmaf(wx0[r][3], lx0[3], s);
                        s = fmaf(wx1[r][0], lx1[0], s);
                        s = fmaf(wx1[r][1], lx1[1], s);
                        s = fmaf(wx1[r][2], lx1[2], s);
                        s = fmaf(wx1[r][3], lx1[3], s);
                        s = fmaf(wh0[r][0], h0a[0], s);
                        s = fmaf(wh0[r][1], h0a[1], s);
                        s = fmaf(wh0[r][2], h0a[2], s);
                        s = fmaf(wh0[r][3], h0a[3], s);
                        s = fmaf(wh1[r][0], h0b[0], s);
                        s = fmaf(wh1[r][1], h0b[1], s);
                        s = fmaf(wh1[r][2], h0b[2], s);
                        s = fmaf(wh1[r][3], h0b[3], s);
                        vv[r] = s;
                    }
                    const float sum = reduce4(vv, lane);
                    const float hv = fast_tanh(sum + bias);
                    uenc = __float_as_uint(hv) ^ em_cur;
                }
                if (lane < 4)
                    coh_store_u(h0_ring + (((size_t)slot << 6) + eg0 + q) * 512 + rowbase + lane, uenc);
            }
            if (havepf) {
                *(f32x4*)&sxn[(se << 9) + (lane << 2)] = px0;
                *(f32x4*)&sxn[(se << 9) + 256 + (lane << 2)] = px1;
            }
            __syncthreads();                       // barrier 2
        }
    } else {
        // ---- layer 1 ----
        for (int t = 0; t < Tg; ++t) {
            const int slot = t & 7, pslot = (t - 1) & 7;
            const unsigned em0 = ((t >> 3) & 1) ? 0xFFFFFFFFu : 0u;          // h0(t)
            const unsigned em1 = (((t - 1) >> 3) & 1) ? 0xFFFFFFFFu : 0u;    // h1(t-1)

            // ---- stage h0(t) -> sh and h1(t-1) -> sh1, validity-retry ----
            const float* p0 = h0_ring + (((size_t)slot << 6) + seg) * 512 + (lane << 2);
            if (t > 0) {
                const float* p1 = h1_ring + (((size_t)pslot << 6) + seg) * 512 + (lane << 2);
                f32x4 d0a, d0b, d1a, d1b;
                for (;;) {
                    f32x4 a, b, c2, d2;
                    coh_ld4k(p0, p1, a, b, c2, d2);
                    unsigned o = 0;
#pragma unroll
                    for (int m = 0; m < 4; ++m) {
                        unsigned u0 = __float_as_uint(a[m])  ^ em0; o |= u0; d0a[m] = __uint_as_float(u0);
                        unsigned u1 = __float_as_uint(b[m])  ^ em0; o |= u1; d0b[m] = __uint_as_float(u1);
                        unsigned u2 = __float_as_uint(c2[m]) ^ em1; o |= u2; d1a[m] = __uint_as_float(u2);
                        unsigned u3 = __float_as_uint(d2[m]) ^ em1; o |= u3; d1b[m] = __uint_as_float(u3);
                    }
                    if (!__any((o >> 30) & 1)) break;
                    if (--budget < 0) break;
                }
                *(f32x4*)&sh[(se << 9) + (lane << 2)] = d0a;
                *(f32x4*)&sh[(se << 9) + 256 + (lane << 2)] = d0b;
                *(f32x4*)&sh1[(se << 9) + (lane << 2)] = d1a;
                *(f32x4*)&sh1[(se << 9) + 256 + (lane << 2)] = d1b;
            } else {
                f32x4 d0a, d0b;
                for (;;) {
                    f32x4 a, b;
                    coh_ld2k(p0, a, b);
                    unsigned o = 0;
#pragma unroll
                    for (int m = 0; m < 4; ++m) {
                        unsigned u0 = __float_as_uint(a[m]) ^ em0; o |= u0; d0a[m] = __uint_as_float(u0);
                        unsigned u1 = __float_as_uint(b[m]) ^ em0; o |= u1; d0b[m] = __uint_as_float(u1);
                    }
                    if (!__any((o >> 30) & 1)) break;
                    if (--budget < 0) break;
                }
                *(f32x4*)&sh[(se << 9) + (lane << 2)] = d0a;
                *(f32x4*)&sh[(se << 9) + 256 + (lane << 2)] = d0b;
                f32x4 z = 0;
                *(f32x4*)&sh1[(se << 9) + (lane << 2)] = z;
                *(f32x4*)&sh1[(se << 9) + 256 + (lane << 2)] = z;
            }
            __syncthreads();                       // barrier 1: staged
            if (tid == 0) flag_store(myflag, (unsigned)(t + 1));   // consumed t (backpressure)

#pragma unroll
            for (int q = 0; q < 4; ++q) {
                unsigned uenc = em0;               // encoded 0.0 for finished elems
                const bool live = (t < sl4[q]);
                float hv = 0.f;
                if (live) {
                    const int el = (we << 2) + q;
                    const f32x4 xa = *(const f32x4*)&sh[(el << 9) + (lane << 2)];
                    const f32x4 xb = *(const f32x4*)&sh[(el << 9) + 256 + (lane << 2)];
                    const f32x4 ha = *(const f32x4*)&sh1[(el << 9) + (lane << 2)];
                    const f32x4 hb = *(const f32x4*)&sh1[(el << 9) + 256 + (lane << 2)];
                    float vv[4];
#pragma unroll
                    for (int r = 0; r < 4; ++r) {
                        float s = wx0[r][0] * xa[0];
                        s = fmaf(wx0[r][1], xa[1], s);
                        s = fmaf(wx0[r][2], xa[2], s);
                        s = fmaf(wx0[r][3], xa[3], s);
                        s = fmaf(wx1[r][0], xb[0], s);
                        s = fmaf(wx1[r][1], xb[1], s);
                        s = fmaf(wx1[r][2], xb[2], s);
                        s = fmaf(wx1[r][3], xb[3], s);
                        s = fmaf(wh0[r][0], ha[0], s);
                        s = fmaf(wh0[r][1], ha[1], s);
                        s = fmaf(wh0[r][2], ha[2], s);
                        s = fmaf(wh0[r][3], ha[3], s);
                        s = fmaf(wh1[r][0], hb[0], s);
                        s = fmaf(wh1[r][1], hb[1], s);
                        s = fmaf(wh1[r][2], hb[2], s);
                        s = fmaf(wh1[r][3], hb[3], s);
                        vv[r] = s;
                    }
                    const float sum = reduce4(vv, lane);
                    hv = fast_tanh(sum + bias);
                    uenc = __float_as_uint(hv) ^ em0;
                }
                if (lane < 4) {
                    coh_store_u(h1_ring + (((size_t)slot << 6) + eg0 + q) * 512 + rowbase + lane, uenc);
                    if (live && t == sl4[q] - 1)
                        h1_final[((size_t)(eg0 + q) << 9) + rowbase + lane] = hv;
                }
            }
            __syncthreads();                       // barrier 2
        }
    }
}

// ---- final head: y = Wyh[1] @ h1 + b_y[1]; out = Wf @ y + bf ----
__device__ __forceinline__ float dot4(float4 a, float4 b) {
    return fmaf(a.x, b.x, fmaf(a.y, b.y, fmaf(a.z, b.z, a.w * b.w)));
}
__device__ __forceinline__ float wave_reduce(float acc) {
#pragma unroll
    for (int off = 32; off > 0; off >>= 1) acc += __shfl_down(acc, off, 64);
    return acc;
}

__global__ __launch_bounds__(512) void head_kernel(
    const float* __restrict__ h1f, const float* __restrict__ Wyh,
    const float* __restrict__ b_y, const float* __restrict__ Wf,
    const float* __restrict__ bf, float* __restrict__ out)
{
    const int e = blockIdx.x;
    const int tid = threadIdx.x, wid = tid >> 6, lane = tid & 63;
    const int k0 = lane << 3;
    __shared__ float sh[H_];
    __shared__ float sy[H_];
    sh[tid] = h1f[(size_t)e * H_ + tid];
    __syncthreads();
    const float4 hA = *(const float4*)&sh[k0];
    const float4 hB = *(const float4*)&sh[k0 + 4];
    const float* Wy1 = Wyh + H_ * H_;
#pragma unroll 4
    for (int rr = 0; rr < 64; ++rr) {
        const int row = (wid << 6) + rr;
        float acc = wave_reduce(dot4(*(const float4*)&Wy1[(size_t)row * H_ + k0], hA) +
                                dot4(*(const float4*)&Wy1[(size_t)row * H_ + k0 + 4], hB));
        if (lane == 0) sy[row] = acc + b_y[H_ + row];
    }
    __syncthreads();
    const float4 yA = *(const float4*)&sy[k0];
    const float4 yB = *(const float4*)&sy[k0 + 4];
#pragma unroll
    for (int rr = 0; rr < 4; ++rr) {
        const int o = (wid << 2) + rr;
        float acc = wave_reduce(dot4(*(const float4*)&Wf[(size_t)o * H_ + k0], yA) +
                                dot4(*(const float4*)&Wf[(size_t)o * H_ + k0 + 4], yB));
        if (lane == 0) out[(size_t)e * O_ + o] = acc + bf[o];
    }
}

// ---- fallback (round-0, known-passing) ----
__global__ __launch_bounds__(1024, 1) void rnn_fused_fb(
    const int* __restrict__ x, const int* __restrict__ seq_lens,
    const float* __restrict__ emb, const float* __restrict__ Whx,
    const float* __restrict__ Whh, const float* __restrict__ b_h,
    const float* __restrict__ Wyh, const float* __restrict__ b_y,
    const float* __restrict__ Wf, const float* __restrict__ bf,
    float* __restrict__ out)
{
    const int b = blockIdx.x, tid = threadIdx.x;
    const int wave = tid >> 6, lane = tid & 63, k0 = lane << 3;
    __shared__ float s_inp[E_];
    __shared__ float s_h0[2][H_];
    __shared__ float s_h1[2][H_];
    __shared__ float s_y[H_];
    if (tid < H_) { s_h0[0][tid]=0.f; s_h0[1][tid]=0.f; s_h1[0][tid]=0.f; s_h1[1][tid]=0.f; }
    const int Tb = seq_lens[b];
    const float* Whx0 = Whx; const float* Whx1 = Whx + H_*E_;
    const float* Whh0 = Whh; const float* Whh1 = Whh + H_*H_;
    for (int t = 0; t < Tb; ++t) {
        const int cur = t & 1, prv = cur ^ 1;
        if (tid < E_) { const int tok = x[b*T_+t]; s_inp[tid] = emb[(size_t)tok*E_+tid]; }
        __syncthreads();
        const float4 iA = *(const float4*)&s_inp[k0], iB = *(const float4*)&s_inp[k0+4];
        const float4 pA = *(const float4*)&s_h0[prv][k0], pB = *(const float4*)&s_h0[prv][k0+4];
#pragma unroll 4
        for (int r = 0; r < 32; ++r) {
            const int i = (wave<<5)+r;
            float acc = dot4(*(const float4*)&Whx0[i*E_+k0], iA) + dot4(*(const float4*)&Whx0[i*E_+k0+4], iB)
                      + dot4(*(const float4*)&Whh0[i*H_+k0], pA) + dot4(*(const float4*)&Whh0[i*H_+k0+4], pB);
            acc = wave_reduce(acc);
            if (lane == 0) s_h0[cur][i] = tanhf(acc + b_h[i]);
        }
        __syncthreads();
        const float4 cA = *(const float4*)&s_h0[cur][k0], cB = *(const float4*)&s_h0[cur][k0+4];
        const float4 qA = *(const float4*)&s_h1[prv][k0], qB = *(const float4*)&s_h1[prv][k0+4];
#pragma unroll 4
        for (int r = 0; r < 32; ++r) {
            const int i = (wave<<5)+r;
            float acc = dot4(*(const float4*)&Whx1[i*E_+k0], cA) + dot4(*(const float4*)&Whx1[i*E_+k0+4], cB)
                      + dot4(*(const float4*)&Whh1[i*H_+k0], qA) + dot4(*(const float4*)&Whh1[i*H_+k0+4], qB);
            acc = wave_reduce(acc);
            if (lane == 0) s_h1[cur][i] = tanhf(acc + b_h[H_+i]);
        }
        __syncthreads();
    }
    const int lastb = (Tb-1) & 1;
    const float4 hA = *(const float4*)&s_h1[lastb][k0], hB = *(const float4*)&s_h1[lastb][k0+4];
    const float* Wy1 = Wyh + H_*H_;
#pragma unroll 4
    for (int r = 0; r < 32; ++r) {
        const int i = (wave<<5)+r;
        float acc = wave_reduce(dot4(*(const float4*)&Wy1[i*H_+k0], hA) + dot4(*(const float4*)&Wy1[i*H_+k0+4], hB));
        if (lane == 0) s_y[i] = acc + b_y[H_+i];
    }
    __syncthreads();
    const float4 yA = *(const float4*)&s_y[k0], yB = *(const float4*)&s_y[k0+4];
    if (wave < 8) {
#pragma unroll
        for (int r = 0; r < 4; ++r) {
            const int o = (wave<<2)+r;
            float acc = wave_reduce(dot4(*(const float4*)&Wf[o*H_+k0], yA) + dot4(*(const float4*)&Wf[o*H_+k0+4], yB));
            if (lane == 0) out[b*O_+o] = acc + bf[o];
        }
    }
}

extern "C" void kernel_launch(void* const* d_in, const int* in_sizes, int n_in,
                              void* d_out, int out_size, void* d_ws, size_t ws_size,
                              hipStream_t stream) {
    const int*   x    = (const int*)d_in[0];
    const int*   sl   = (const int*)d_in[1];
    const float* emb  = (const float*)d_in[2];
    const float* Whx  = (const float*)d_in[3];
    const float* Whh  = (const float*)d_in[4];
    const float* b_h  = (const float*)d_in[5];
    const float* Wyh  = (const float*)d_in[6];
    const float* b_y  = (const float*)d_in[7];
    const float* Wf   = (const float*)d_in[8];
    const float* bf   = (const float*)d_in[9];
    float* out = (float*)d_out;

    if (ws_size < WS_REQUIRED) {
        rnn_fused_fb<<<B_, 1024, 0, stream>>>(x, sl, emb, Whx, Whh, b_h, Wyh, b_y, Wf, bf, out);
        return;
    }

    float* ws_f = (float*)d_ws;
    float* h0_ring = ws_f + H0_OFF;
    float* h1_ring = ws_f + H1_OFF;
    float* h1f     = ws_f + HF_OFF;
    unsigned* flags = (unsigned*)(ws_f + FLAG_OFF);

    // rings poisoned to 0xFF (exponent 255 -> stale for epoch 0); flags zeroed
    hipMemsetAsync(h0_ring, 0xFF, 2 * H1_OFF * sizeof(float), stream);
    hipMemsetAsync(flags, 0, FLAG_UINTS * sizeof(unsigned), stream);
    rnn_pipe11<<<512, 512, 0, stream>>>(x, sl, emb, Whx, Whh, b_h,
                                        h0_ring, h1_ring, h1f, flags);
    head_kernel<<<B_, 512, 0, stream>>>(h1f, Wyh, b_y, Wf, bf, out);
}